// Round 4
// baseline (91.200 us; speedup 1.0000x reference)
//
#include <hip/hip_runtime.h>

// Blobber: out = sig2(box3(sig1(box3(in)))) — iterations collapse to one.
// in/out: 32 x 1 x 512 x 512 fp32.
//
// R8 = MEASUREMENT ROUND. R5 (occupancy 2x) and R7 (shuffle->LDS) both left
// dur_us pinned at 82-85 us; the blobber dispatch has NEVER appeared in the
// top-5 counter table (cutoff ~41.8 us), so its counters are unknown and all
// models have failed. This version runs the identical R7 pipeline but each
// wave processes TWO images (img and (img+16)&31, duplicate-identical writes
// for the second -> correctness preserved). The blobber dispatch doubles to
// ~75 us -> tops the profile table -> we finally get hbm_gbps / VALUBusy /
// Occupancy for it, and dur_new - 82.4 measures the true kernel time.
// NEXT ROUND: revert the j-loop, apply the counter-directed fix.
//
// Pipeline per s1 row r: v3 = in(r-1)+in(r)+in(r+1) (rows zero-padded);
// s1 = sig1(h3(v3)), forced 0 for OOB rows; h2 = h3(s1);
// out(y) = sig2(h2(y-1)+h2(y)+h2(y+1)).

#define IMG 512
#define BH  4             // output rows per wave
#define NIT (BH + 2)      // 6 s1/h2 rows
#define BUFW 520          // 4 pad | 512 | 4 pad

typedef float vf4 __attribute__((ext_vector_type(4)));   // nontemporal-store-able

// sigmoid((sum9/9 - c)*1000) = sigmoid(fma(sum9, 1000/9, -1000c))
__device__ __forceinline__ float steep_sig(float sum9, float bias) {
    float x = fmaf(sum9, 1000.0f / 9.0f, bias);
    return __builtin_amdgcn_rcpf(1.0f + __expf(-x));
}

__device__ __forceinline__ float4 f4add3(float4 a, float4 b, float4 c) {
    return make_float4(a.x + b.x + c.x, a.y + b.y + c.y,
                       a.z + b.z + c.z, a.w + b.w + c.w);
}

__device__ __forceinline__ void nt_store4(float* p, float x, float y, float z, float w) {
    vf4 v = {x, y, z, w};
    __builtin_nontemporal_store(v, (vf4*)p);
}

__global__ __launch_bounds__(256) void blobber_fused(const float* __restrict__ in,
                                                     float* __restrict__ out) {
    __shared__ float vbuf[4][BUFW];   // v3 row, one per wave
    __shared__ float sbuf[4][BUFW];   // s1 row, one per wave

    const int tid  = threadIdx.x;
    const int lane = tid & 63;
    const int wid  = tid >> 6;
    const int gw   = blockIdx.x * 4 + wid;          // 4096 waves
    const int band = gw & 127;                      // 128 bands x 4 rows
    const int img0 = gw >> 7;                       // 32 images
    const int y0   = band * BH;

    float* vb = vbuf[wid];
    float* sb = sbuf[wid];

    // zero the pads once (cols -4..-1 and 512..515); never overwritten
    if (lane < 4) {
        vb[lane] = 0.0f; vb[516 + lane] = 0.0f;
        sb[lane] = 0.0f; sb[516 + lane] = 0.0f;
    }
    __builtin_amdgcn_wave_barrier();

    const int colL = 4 * lane;         // L half: cols 0..255, coalesced
    const int colR = 256 + 4 * lane;   // R half: cols 256..511, coalesced
    const int bL   = 4 + colL;         // LDS index of own L cols
    const int bR   = 4 + colR;         // LDS index of own R cols

    const float4 z4 = make_float4(0.f, 0.f, 0.f, 0.f);

    // PROBE: two passes over different images; pass 1 duplicates the work of
    // the wave that owns (band, img0+16) and writes identical bytes (safe).
    for (int j = 0; j < 2; ++j) {
        const int img = (img0 + 16 * j) & 31;
        const float* ip = in  + (size_t)img * (IMG * IMG);
        float*       op = out + (size_t)img * (IMG * IMG);

        // ---- rolling window: a,b,c = input rows r-1, r, r+1 ----
        float4 aL = z4, bLw = z4, cL = z4, aR = z4, bRw = z4, cR = z4;
        if (y0 - 2 >= 0) {                              // wave-uniform
            aL = *(const float4*)(ip + (y0 - 2) * IMG + colL);
            aR = *(const float4*)(ip + (y0 - 2) * IMG + colR);
        }
        if (y0 - 1 >= 0) {                              // wave-uniform
            bLw = *(const float4*)(ip + (y0 - 1) * IMG + colL);
            bRw = *(const float4*)(ip + (y0 - 1) * IMG + colR);
        }
        cL = *(const float4*)(ip + y0 * IMG + colL);    // y0 always in range
        cR = *(const float4*)(ip + y0 * IMG + colR);

        float4 h2mL = z4, h2cL = z4, h2mR = z4, h2cR = z4;

        #pragma unroll
        for (int s = 0; s < NIT; ++s) {
            const int r = y0 - 1 + s;                   // s1/h2 row produced

            // prefetch input row r+2 (becomes c after the shift)
            float4 nL = z4, nR = z4;
            if (s < NIT - 1) {
                const int pr = r + 2;                   // y0+1+s, always >= 1
                if (pr < IMG) {                         // wave-uniform
                    nL = *(const float4*)(ip + pr * IMG + colL);
                    nR = *(const float4*)(ip + pr * IMG + colR);
                }
            }

            // vertical 3-sum (input rows r-1..r+1)
            float4 vL = f4add3(aL, bLw, cL);
            float4 vR = f4add3(aR, bRw, cR);

            // publish v3 row to wave-private LDS row buffer
            *(float4*)(vb + bL) = vL;
            *(float4*)(vb + bR) = vR;
            __builtin_amdgcn_wave_barrier();
            float vLl = vb[bL - 1], vLr = vb[bL + 4];
            float vRl = vb[bR - 1], vRr = vb[bR + 4];

            // stage 1: s1 = sig1(h3(v3)); OOB rows are literal 0
            float4 s1L, s1R;
            if ((unsigned)r < IMG) {                    // wave-uniform
                s1L.x = steep_sig(vLl  + vL.x + vL.y, -10.0f);
                s1L.y = steep_sig(vL.x + vL.y + vL.z, -10.0f);
                s1L.z = steep_sig(vL.y + vL.z + vL.w, -10.0f);
                s1L.w = steep_sig(vL.z + vL.w + vLr,  -10.0f);
                s1R.x = steep_sig(vRl  + vR.x + vR.y, -10.0f);
                s1R.y = steep_sig(vR.x + vR.y + vR.z, -10.0f);
                s1R.z = steep_sig(vR.y + vR.z + vR.w, -10.0f);
                s1R.w = steep_sig(vR.z + vR.w + vRr,  -10.0f);
            } else {
                s1L = z4; s1R = z4;
            }

            // publish s1 row, read its neighbors
            *(float4*)(sb + bL) = s1L;
            *(float4*)(sb + bR) = s1R;
            __builtin_amdgcn_wave_barrier();
            float sLl = sb[bL - 1], sLr = sb[bL + 4];
            float sRl = sb[bR - 1], sRr = sb[bR + 4];

            // stage 2 horizontal: h2 = h3(s1)
            float4 h2pL, h2pR;
            h2pL.x = sLl   + s1L.x + s1L.y;
            h2pL.y = s1L.x + s1L.y + s1L.z;
            h2pL.z = s1L.y + s1L.z + s1L.w;
            h2pL.w = s1L.z + s1L.w + sLr;
            h2pR.x = sRl   + s1R.x + s1R.y;
            h2pR.y = s1R.x + s1R.y + s1R.z;
            h2pR.z = s1R.y + s1R.z + s1R.w;
            h2pR.w = s1R.z + s1R.w + sRr;

            // output row r-1 = sig2(vertical 3-sum of h2 rows r-2..r)
            if (s >= 2) {
                const int oy = r - 1;                   // y0 .. y0+3
                nt_store4(op + oy * IMG + colL,
                          steep_sig(h2mL.x + h2cL.x + h2pL.x, -900.0f),
                          steep_sig(h2mL.y + h2cL.y + h2pL.y, -900.0f),
                          steep_sig(h2mL.z + h2cL.z + h2pL.z, -900.0f),
                          steep_sig(h2mL.w + h2cL.w + h2pL.w, -900.0f));
                nt_store4(op + oy * IMG + colR,
                          steep_sig(h2mR.x + h2cR.x + h2pR.x, -900.0f),
                          steep_sig(h2mR.y + h2cR.y + h2pR.y, -900.0f),
                          steep_sig(h2mR.z + h2cR.z + h2pR.z, -900.0f),
                          steep_sig(h2mR.w + h2cR.w + h2pR.w, -900.0f));
            }

            h2mL = h2cL; h2cL = h2pL;
            h2mR = h2cR; h2cR = h2pR;

            // shift the rolling window
            aL = bLw; bLw = cL; cL = nL;
            aR = bRw; bRw = cR; cR = nR;
            // next writes must not pass this iteration's reads
            __builtin_amdgcn_wave_barrier();
        }
    }
}

extern "C" void kernel_launch(void* const* d_in, const int* in_sizes, int n_in,
                              void* d_out, int out_size, void* d_ws, size_t ws_size,
                              hipStream_t stream) {
    const float* in  = (const float*)d_in[0];
    float*       out = (float*)d_out;
    // 4096 waves = 1024 blocks x 4 waves (32 imgs x 128 bands), 2 images/wave
    blobber_fused<<<dim3(1024), dim3(256), 0, stream>>>(in, out);
}

// Round 5
// 82.461 us; speedup vs baseline: 1.1060x; 1.1060x over previous
//
#include <hip/hip_runtime.h>

// Blobber: out = sig2(box3(sig1(box3(in)))) — the reference's 4 iterations all
// restart from `inputs`, so they collapse to one iteration.
// in/out: 32 x 1 x 512 x 512 fp32.
//
// R9 = revert of the R8 measurement probe, back to the verified R7 kernel.
//
// R8 FINDING (the key fact of this session): doubling the kernel's work moved
// dur_us 82.4 -> 91.2, so the kernel itself costs ~9 us. The other ~73 us of
// dur_us is harness floor: the 256 MiB workspace re-poison fill (~43 us) +
// dozens of small reset dispatches + launch gaps. This is why occupancy (R5)
// and shuffle->LDS (R7) changes were invisible. At ~9 us the kernel sits at
// its compulsory-traffic roofline (67 MB / 6.3 TB/s ~= 10.6 us, minus L3
// read absorption). No kernel-side headroom remains above the noise band.
//
// Pipeline per s1 row r: v3 = in(r-1)+in(r)+in(r+1) (rows zero-padded);
// s1 = sig1(h3(v3)), forced 0 for OOB rows (conv2 zero-pads s1 itself,
// NOT sig1(0)=4.5e-5); h2 = h3(s1); out(y) = sig2(h2(y-1)+h2(y)+h2(y+1)).

#define IMG 512
#define BH  4             // output rows per wave
#define NIT (BH + 2)      // 6 s1/h2 rows
#define BUFW 520          // 4 pad | 512 | 4 pad

typedef float vf4 __attribute__((ext_vector_type(4)));   // nontemporal-store-able

// sigmoid((sum9/9 - c)*1000) = sigmoid(fma(sum9, 1000/9, -1000c))
__device__ __forceinline__ float steep_sig(float sum9, float bias) {
    float x = fmaf(sum9, 1000.0f / 9.0f, bias);
    return __builtin_amdgcn_rcpf(1.0f + __expf(-x));
}

__device__ __forceinline__ float4 f4add3(float4 a, float4 b, float4 c) {
    return make_float4(a.x + b.x + c.x, a.y + b.y + c.y,
                       a.z + b.z + c.z, a.w + b.w + c.w);
}

__device__ __forceinline__ void nt_store4(float* p, float x, float y, float z, float w) {
    vf4 v = {x, y, z, w};
    __builtin_nontemporal_store(v, (vf4*)p);
}

__global__ __launch_bounds__(256) void blobber_fused(const float* __restrict__ in,
                                                     float* __restrict__ out) {
    __shared__ float vbuf[4][BUFW];   // v3 row, one per wave
    __shared__ float sbuf[4][BUFW];   // s1 row, one per wave

    const int tid  = threadIdx.x;
    const int lane = tid & 63;
    const int wid  = tid >> 6;
    const int gw   = blockIdx.x * 4 + wid;          // 4096 waves
    const int band = gw & 127;                      // 128 bands x 4 rows
    const int img  = gw >> 7;                       // 32 images
    const int y0   = band * BH;

    float* vb = vbuf[wid];
    float* sb = sbuf[wid];

    // zero the pads once (cols -4..-1 and 512..515); never overwritten
    if (lane < 4) {
        vb[lane] = 0.0f; vb[516 + lane] = 0.0f;
        sb[lane] = 0.0f; sb[516 + lane] = 0.0f;
    }
    __builtin_amdgcn_wave_barrier();

    const int colL = 4 * lane;         // L half: cols 0..255, coalesced
    const int colR = 256 + 4 * lane;   // R half: cols 256..511, coalesced
    const int bL   = 4 + colL;         // LDS index of own L cols
    const int bR   = 4 + colR;         // LDS index of own R cols

    const float* ip = in  + (size_t)img * (IMG * IMG);
    float*       op = out + (size_t)img * (IMG * IMG);

    const float4 z4 = make_float4(0.f, 0.f, 0.f, 0.f);

    // ---- rolling window: a,b,c = input rows r-1, r, r+1 for current s ----
    float4 aL = z4, bLw = z4, cL = z4, aR = z4, bRw = z4, cR = z4;
    if (y0 - 2 >= 0) {                              // wave-uniform
        aL = *(const float4*)(ip + (y0 - 2) * IMG + colL);
        aR = *(const float4*)(ip + (y0 - 2) * IMG + colR);
    }
    if (y0 - 1 >= 0) {                              // wave-uniform
        bLw = *(const float4*)(ip + (y0 - 1) * IMG + colL);
        bRw = *(const float4*)(ip + (y0 - 1) * IMG + colR);
    }
    cL = *(const float4*)(ip + y0 * IMG + colL);    // y0 always in range
    cR = *(const float4*)(ip + y0 * IMG + colR);

    float4 h2mL = z4, h2cL = z4, h2mR = z4, h2cR = z4;

    #pragma unroll
    for (int s = 0; s < NIT; ++s) {
        const int r = y0 - 1 + s;                   // s1/h2 row being produced

        // prefetch input row r+2 (becomes c after the shift)
        float4 nL = z4, nR = z4;
        if (s < NIT - 1) {
            const int pr = r + 2;                   // y0+1+s, always >= 1
            if (pr < IMG) {                         // wave-uniform
                nL = *(const float4*)(ip + pr * IMG + colL);
                nR = *(const float4*)(ip + pr * IMG + colR);
            }
        }

        // vertical 3-sum (input rows r-1..r+1)
        float4 vL = f4add3(aL, bLw, cL);
        float4 vR = f4add3(aR, bRw, cR);

        // publish v3 row to wave-private LDS row buffer
        *(float4*)(vb + bL) = vL;
        *(float4*)(vb + bR) = vR;
        __builtin_amdgcn_wave_barrier();
        // neighbors: v3[col-1], v3[col+4] per half (pads give image edges;
        // the 255/256 seam is just the other half's write)
        float vLl = vb[bL - 1], vLr = vb[bL + 4];
        float vRl = vb[bR - 1], vRr = vb[bR + 4];

        // stage 1: s1 = sig1(h3(v3)); OOB rows are literal 0
        float4 s1L, s1R;
        if ((unsigned)r < IMG) {                    // wave-uniform
            s1L.x = steep_sig(vLl  + vL.x + vL.y, -10.0f);
            s1L.y = steep_sig(vL.x + vL.y + vL.z, -10.0f);
            s1L.z = steep_sig(vL.y + vL.z + vL.w, -10.0f);
            s1L.w = steep_sig(vL.z + vL.w + vLr,  -10.0f);
            s1R.x = steep_sig(vRl  + vR.x + vR.y, -10.0f);
            s1R.y = steep_sig(vR.x + vR.y + vR.z, -10.0f);
            s1R.z = steep_sig(vR.y + vR.z + vR.w, -10.0f);
            s1R.w = steep_sig(vR.z + vR.w + vRr,  -10.0f);
        } else {
            s1L = z4; s1R = z4;
        }

        // publish s1 row, read its neighbors
        *(float4*)(sb + bL) = s1L;
        *(float4*)(sb + bR) = s1R;
        __builtin_amdgcn_wave_barrier();
        float sLl = sb[bL - 1], sLr = sb[bL + 4];
        float sRl = sb[bR - 1], sRr = sb[bR + 4];

        // stage 2 horizontal: h2 = h3(s1)
        float4 h2pL, h2pR;
        h2pL.x = sLl   + s1L.x + s1L.y;
        h2pL.y = s1L.x + s1L.y + s1L.z;
        h2pL.z = s1L.y + s1L.z + s1L.w;
        h2pL.w = s1L.z + s1L.w + sLr;
        h2pR.x = sRl   + s1R.x + s1R.y;
        h2pR.y = s1R.x + s1R.y + s1R.z;
        h2pR.z = s1R.y + s1R.z + s1R.w;
        h2pR.w = s1R.z + s1R.w + sRr;

        // output row r-1 = sig2(vertical 3-sum of h2 rows r-2..r)
        if (s >= 2) {
            const int oy = r - 1;                   // y0 .. y0+3
            nt_store4(op + oy * IMG + colL,
                      steep_sig(h2mL.x + h2cL.x + h2pL.x, -900.0f),
                      steep_sig(h2mL.y + h2cL.y + h2pL.y, -900.0f),
                      steep_sig(h2mL.z + h2cL.z + h2pL.z, -900.0f),
                      steep_sig(h2mL.w + h2cL.w + h2pL.w, -900.0f));
            nt_store4(op + oy * IMG + colR,
                      steep_sig(h2mR.x + h2cR.x + h2pR.x, -900.0f),
                      steep_sig(h2mR.y + h2cR.y + h2pR.y, -900.0f),
                      steep_sig(h2mR.z + h2cR.z + h2pR.z, -900.0f),
                      steep_sig(h2mR.w + h2cR.w + h2pR.w, -900.0f));
        }

        h2mL = h2cL; h2cL = h2pL;
        h2mR = h2cR; h2cR = h2pR;

        // shift the rolling window
        aL = bLw; bLw = cL; cL = nL;
        aR = bRw; bRw = cR; cR = nR;
        // next iteration's LDS writes must not pass this iteration's reads
        __builtin_amdgcn_wave_barrier();
    }
}

extern "C" void kernel_launch(void* const* d_in, const int* in_sizes, int n_in,
                              void* d_out, int out_size, void* d_ws, size_t ws_size,
                              hipStream_t stream) {
    const float* in  = (const float*)d_in[0];
    float*       out = (float*)d_out;
    // 4096 waves = 1024 blocks x 4 waves (32 imgs x 128 bands)
    blobber_fused<<<dim3(1024), dim3(256), 0, stream>>>(in, out);
}